// Round 11
// baseline (599.373 us; speedup 1.0000x reference)
//
#include <hip/hip_runtime.h>
#include <hip/hip_cooperative_groups.h>
#include <math.h>

namespace cg = cooperative_groups;

#define NPT 8192
#define HWIMG 19200
#define KCAP 128

using short8 = __attribute__((ext_vector_type(8))) short;
using short4v = __attribute__((ext_vector_type(4))) short;
using f32x4  = __attribute__((ext_vector_type(4))) float;

__device__ __forceinline__ float lrelu(float x) { return x > 0.f ? x : 0.01f * x; }
__device__ __forceinline__ unsigned short f2bf(float v) {
  unsigned u = __float_as_uint(v);
  return (unsigned short)((u + 0x7fffu + ((u >> 16) & 1u)) >> 16);
}
__device__ __forceinline__ float bf2f(unsigned short h) {
  return __uint_as_float(((unsigned)h) << 16);
}
__device__ __forceinline__ void split2(float v, unsigned short& h, unsigned short& l) {
  h = f2bf(v);
  l = f2bf(v - bf2f(h));
}
__device__ __forceinline__ void mfma3(f32x4& acc, short8 ah, short8 al, short8 wh, short8 wl) {
  acc = __builtin_amdgcn_mfma_f32_16x16x32_bf16(ah, wh, acc, 0, 0, 0);
  acc = __builtin_amdgcn_mfma_f32_16x16x32_bf16(al, wh, acc, 0, 0, 0);
  acc = __builtin_amdgcn_mfma_f32_16x16x32_bf16(ah, wl, acc, 0, 0, 0);
}
__device__ __forceinline__ int swz(int o, int k, int Kc) {
  return ((((o >> 4) * Kc + (k >> 5)) << 6) + (((k >> 3) & 3) << 4) + (o & 15)) * 8 + (k & 7);
}

// weight-plane segment offsets (in shorts)
#define OFF_PCONV2  0
#define OFF_CONV1   8192
#define OFF_CONV2   10240
#define OFF_PSCONV1 18432
#define OFF_PSCONV2 51200
#define OFF_FINAL   83968
#define OFF_W3      137216
#define OFF_W2P     186368

#define S_C4    NPT
#define S_G     129
#define S_BIASC 128
#define S_B2C   64
#define S_FEAT  (NPT*32)
#define S_W3    49152
#define S_W2P   8192
#define S_WSPL  OFF_W3
#define PREP_TOTAL (S_C4 + S_G + S_BIASC + S_B2C + S_FEAT + S_W3 + S_W2P + S_WSPL)

struct Args {
  const float *seg, *img, *cloud, *tvec;
  const int* choose;
  const float *pconv1_w, *pconv1_b, *pconv2_w, *pconv2_b;
  const float *conv1_w, *conv1_b, *conv2_w, *conv2_b;
  const float *psconv1_w, *psconv1_b, *psconv2_w, *psconv2_b;
  const float *final_w, *final_b;
  const float *seg1_w, *seg1_b, *seg2_w, *seg2_b, *seg3_w, *seg3_b;
  const float *dis1_w, *dis1_b, *dis2_w, *dis2_b, *dis3_w, *dis3_b;
  const float *lin1_w, *lin1_b, *lin2_w, *lin2_b, *lin3_w, *lin3_b;
  float *c4, *g, *biasc, *bias2c, *feat, *pf, *Yf, *Yfp, *wsm;
  int* idx;
  unsigned short *feat_h, *feat_l, *fusedh, *fusedl, *Wh, *Wl;
  float *o_kp, *o_disp, *o_dc, *o_segp;
};

// ---------------- bitonic helpers ---------------------------------------------
__device__ __forceinline__ unsigned bsort32u(unsigned key, int lane) {
#pragma unroll
  for (int k = 2; k <= 64; k <<= 1) {
#pragma unroll
    for (int j = k >> 1; j > 0; j >>= 1) {
      unsigned o = __shfl_xor(key, j, 64);
      bool keepmin = (((lane & j) == 0) == ((lane & k) == 0));
      key = ((o < key) == keepmin) ? o : key;
    }
  }
  return key;
}
__device__ __forceinline__ unsigned long long bsort64(unsigned long long key, int lane) {
#pragma unroll
  for (int k = 2; k <= 64; k <<= 1) {
#pragma unroll
    for (int j = k >> 1; j > 0; j >>= 1) {
      unsigned long long o = __shfl_xor(key, j, 64);
      bool keepmin = (((lane & j) == 0) == ((lane & k) == 0));
      bool omin = o < key;
      key = (omin == keepmin) ? o : key;
    }
  }
  return key;
}
__device__ __forceinline__ unsigned long long bmerge64(unsigned long long key, int lane) {
#pragma unroll
  for (int j = 32; j > 0; j >>= 1) {
    unsigned long long o = __shfl_xor(key, j, 64);
    bool keepmin = ((lane & j) == 0);
    bool omin = o < key;
    key = (omin == keepmin) ? o : key;
  }
  return key;
}

// ---------------- PA: prep item (grid-strided) ---------------------------------
__device__ void prep_item(const Args& a, int j) {
  if (j < S_C4) {
    float x = a.cloud[j*3+0], y = a.cloud[j*3+1], z = a.cloud[j*3+2];
    float4 v; v.x = x; v.y = y; v.z = z; v.w = x*x + y*y + z*z;
    ((float4*)a.c4)[j] = v;
    return;
  }
  j -= S_C4;
  if (j < S_G) { a.g[j] = 0.f; return; }
  j -= S_G;
  if (j < S_BIASC) { a.biasc[j] = (j < 64) ? a.seg1_b[j] : a.dis1_b[j-64]; return; }
  j -= S_BIASC;
  if (j < S_B2C) { a.bias2c[j] = (j < 32) ? a.seg2_b[j] : a.dis2_b[j-32]; return; }
  j -= S_B2C;
  if (j < S_FEAT) {
    int n = j >> 5, ch = j & 31;
    float v = a.img[ch*HWIMG + a.choose[n]];
    a.feat[j] = v;
    unsigned short hh, ll; split2(v, hh, ll);
    int d = swz(n, ch, 1);
    a.feat_h[d] = hh; a.feat_l[d] = ll;
    return;
  }
  j -= S_FEAT;
  if (j < S_W3) {
    int h = j / 24576, r = j - h*24576, o = r / 384, k = r - o*384;
    int t = k >> 7, c = k & 127;
    float v = (h ? a.dis1_w : a.seg1_w)[o*384 + c*3 + t];
    unsigned short hh, ll; split2(v, hh, ll);
    int d = OFF_W3 + swz(h*64 + o, k, 12);
    a.Wh[d] = hh; a.Wl[d] = ll;
    return;
  }
  j -= S_W3;
  if (j < S_W2P) {
    int o = j >> 7, c = j & 127;
    float v = 0.f;
    if (o < 32) { if (c < 64) v = a.seg2_w[o*64 + c]; }
    else        { if (c >= 64) v = a.dis2_w[(o-32)*64 + (c-64)]; }
    unsigned short hh, ll; split2(v, hh, ll);
    int d = OFF_W2P + swz(o, c, 4);
    a.Wh[d] = hh; a.Wl[d] = ll;
    return;
  }
  j -= S_W2P;
  if (j < S_WSPL) {
    float v; int d;
    if (j < OFF_CONV1) {
      int o = j >> 6, k = j & 63;
      v = a.pconv2_w[j]; d = OFF_PCONV2 + swz(o, k, 2);
    } else if (j < OFF_CONV2) {
      int jj = j - OFF_CONV1, o = jj >> 5, k = jj & 31;
      v = a.conv1_w[jj]; d = OFF_CONV1 + swz(o, k, 1);
    } else if (j < OFF_PSCONV1) {
      int jj = j - OFF_CONV2, o = jj >> 6, k = jj & 63;
      v = a.conv2_w[jj]; d = OFF_CONV2 + swz(o, k, 2);
    } else if (j < OFF_PSCONV2) {
      int jj = j - OFF_PSCONV1, o = jj >> 7, k = jj & 127;
      v = a.psconv1_w[jj]; d = OFF_PSCONV1 + swz(o, k, 4);
    } else if (j < OFF_FINAL) {
      int jj = j - OFF_PSCONV2, o = jj >> 8, k = jj & 255;
      v = a.psconv2_w[jj]; d = OFF_PSCONV2 + swz(o, k, 8);
    } else {
      int jj = j - OFF_FINAL, o = jj / 416, k = jj - o*416;
      v = a.final_w[jj]; d = OFF_FINAL + swz(o, k, 13);
    }
    unsigned short hh, ll; split2(v, hh, ll);
    a.Wh[d] = hh; a.Wl[d] = ll;
  }
}

// ---------------- PA: dis_center (one block) -----------------------------------
__device__ void dc_body(const Args& a, char* smem, int tid) {
  float* sred = (float*)smem;
  int lane = tid & 63, w = tid >> 6;
  float tx = a.tvec[0], ty = a.tvec[1], tz = a.tvec[2];
  float v[32];
  float m = -INFINITY;
#pragma unroll
  for (int i2 = 0; i2 < 32; ++i2) {
    int n = i2*256 + tid;
    float ax = a.cloud[n*3+0] + tx, ay = a.cloud[n*3+1] + ty, az = a.cloud[n*3+2] + tz;
    v[i2] = sqrtf(ax*ax + ay*ay + az*az);
    m = fmaxf(m, v[i2]);
  }
#pragma unroll
  for (int o = 1; o < 64; o <<= 1) m = fmaxf(m, __shfl_xor(m, o, 64));
  if (lane == 0) sred[w] = m;
  __syncthreads();
  m = fmaxf(fmaxf(sred[0], sred[1]), fmaxf(sred[2], sred[3]));
  __syncthreads();
  float s = 0.f;
#pragma unroll
  for (int i2 = 0; i2 < 32; ++i2) { v[i2] = expf(v[i2] - m); s += v[i2]; }
#pragma unroll
  for (int o = 1; o < 64; o <<= 1) s += __shfl_xor(s, o, 64);
  if (lane == 0) sred[w] = s;
  __syncthreads();
  s = sred[0] + sred[1] + sred[2] + sred[3];
#pragma unroll
  for (int i2 = 0; i2 < 32; ++i2) a.o_dc[i2*256 + tid] = v[i2] / s;
}

// ---------------- PB: knn group (4 queries) ------------------------------------
__device__ void knn_body(const Args& a, char* smem, int qb, int tid) {
  float (*smin)[256] = (float(*)[256])smem;
  float* sTv = (float*)(smem + 4096);
  int*   scnt = (int*)(smem + 4112);
  float (*sd)[KCAP] = (float(*)[KCAP])(smem + 4128);
  int   (*sj)[KCAP] = (int(*)[KCAP])(smem + 6176);
  int lane = tid & 63, w = tid >> 6;
  const float4* c4 = (const float4*)a.c4;
  int q0 = qb * 4;
  float4 p0 = c4[q0], p1 = c4[q0+1], p2 = c4[q0+2], p3 = c4[q0+3];
  float p0x = -2.f*p0.x, p0y = -2.f*p0.y, p0z = -2.f*p0.z;
  float p1x = -2.f*p1.x, p1y = -2.f*p1.y, p1z = -2.f*p1.z;
  float p2x = -2.f*p2.x, p2y = -2.f*p2.y, p2z = -2.f*p2.z;
  float p3x = -2.f*p3.x, p3y = -2.f*p3.y, p3z = -2.f*p3.z;
#define DDOT(PX,PY,PZ,PW,CJ) fmaf(PX,(CJ).x, fmaf(PY,(CJ).y, fmaf(PZ,(CJ).z, PW + (CJ).w)))
  float m0 = INFINITY, m1 = INFINITY, m2 = INFINITY, m3 = INFINITY;
  for (int t = 0; t < 32; ++t) {
    float4 cj = c4[t*256 + tid];
    m0 = fminf(m0, DDOT(p0x,p0y,p0z,p0.w,cj));
    m1 = fminf(m1, DDOT(p1x,p1y,p1z,p1.w,cj));
    m2 = fminf(m2, DDOT(p2x,p2y,p2z,p2.w,cj));
    m3 = fminf(m3, DDOT(p3x,p3y,p3z,p3.w,cj));
  }
  smin[0][tid] = m0; smin[1][tid] = m1; smin[2][tid] = m2; smin[3][tid] = m3;
  if (tid < 4) scnt[tid] = 0;
  __syncthreads();
  {
    float4 vv = *(const float4*)&smin[w][lane*4];
    float m4 = fmaxf(fminf(fminf(vv.x, vv.y), fminf(vv.z, vv.w)), 0.f);
    unsigned key = bsort32u(__float_as_uint(m4), lane);
    float T = __uint_as_float(__shfl(key, 31, 64));
    if (lane == 0) sTv[w] = T * (1.f + 2e-5f) + 4e-5f;
  }
  __syncthreads();
  float T0 = sTv[0], T1 = sTv[1], T2 = sTv[2], T3 = sTv[3];
  for (int t = 0; t < 32; ++t) {
    int j = t*256 + tid;
    float4 cj = c4[j];
    float d;
#define APPEND(Q, P) { \
    float dx_ = (P).x-cj.x, dy_ = (P).y-cj.y, dz_ = (P).z-cj.z; \
    float de_ = dx_*dx_ + dy_*dy_ + dz_*dz_; \
    int p_ = atomicAdd(&scnt[Q],1); if (p_ < KCAP) { sd[Q][p_] = de_; sj[Q][p_] = j; } }
    d = DDOT(p0x,p0y,p0z,p0.w,cj); if (d <= T0) APPEND(0, p0);
    d = DDOT(p1x,p1y,p1z,p1.w,cj); if (d <= T1) APPEND(1, p1);
    d = DDOT(p2x,p2y,p2z,p2.w,cj); if (d <= T2) APPEND(2, p2);
    d = DDOT(p3x,p3y,p3z,p3.w,cj); if (d <= T3) APPEND(3, p3);
  }
  __syncthreads();
  int M = scnt[w]; if (M > KCAP) M = KCAP;
  unsigned long long key = (lane < M)
      ? (((unsigned long long)__float_as_uint(sd[w][lane]) << 32) | (unsigned)sj[w][lane])
      : ~0ull;
  key = bsort64(key, lane);
  for (int base = 64; base < M; base += 64) {
    unsigned long long nk = (base + lane < M)
        ? (((unsigned long long)__float_as_uint(sd[w][base+lane]) << 32) | (unsigned)sj[w][base+lane])
        : ~0ull;
    nk = bsort64(nk, lane);
    nk = __shfl_xor(nk, 63, 64);
    key = key < nk ? key : nk;
    key = bmerge64(key, lane);
  }
  float dsel = __uint_as_float((unsigned)(key >> 32));
  int   jsel = (int)(unsigned)(key & 0xffffffffu);
  float v = -sqrtf(dsel);
  float mx = v;
#pragma unroll
  for (int o = 1; o < 32; o <<= 1) mx = fmaxf(mx, __shfl_xor(mx, o, 64));
  float e = expf(v - mx);
  float s = e;
#pragma unroll
  for (int o = 1; o < 32; o <<= 1) s += __shfl_xor(s, o, 64);
  if (lane < 32) {
    int qd = q0 + w;
    a.wsm[qd*32 + lane] = e / s;
    a.idx[qd*32 + lane] = jsel;
  }
}

// ---------------- PB: MLP chain tile -------------------------------------------
__device__ void chain_body(const Args& a, char* smem, int cb, int tid) {
  unsigned short* sh_h = (unsigned short*)smem;
  unsigned short* sh_l = (unsigned short*)(smem + 8192);
  int lane = tid & 63, w = tid >> 6;
  int mr = lane & 15, q = lane >> 4;
  const float4* c4 = (const float4*)a.c4;
  if (cb < 512) {
    int m0 = cb * 16;
    float4 cp = c4[m0 + mr];
    short8 ah0, al0, ah1, al1;
#pragma unroll
    for (int j = 0; j < 8; ++j) {
      int c0 = q*8 + j, c1 = 32 + q*8 + j;
      float v0 = lrelu(fmaf(cp.x, a.pconv1_w[c0*3+0], fmaf(cp.y, a.pconv1_w[c0*3+1],
                        fmaf(cp.z, a.pconv1_w[c0*3+2], a.pconv1_b[c0]))));
      float v1 = lrelu(fmaf(cp.x, a.pconv1_w[c1*3+0], fmaf(cp.y, a.pconv1_w[c1*3+1],
                        fmaf(cp.z, a.pconv1_w[c1*3+2], a.pconv1_b[c1]))));
      unsigned short hh, ll;
      split2(v0, hh, ll); ah0[j] = (short)hh; al0[j] = (short)ll;
      split2(v1, hh, ll); ah1[j] = (short)hh; al1[j] = (short)ll;
    }
    f32x4 acc[2];
#pragma unroll
    for (int t = 0; t < 2; ++t) { f32x4 z = {0.f,0.f,0.f,0.f}; acc[t] = z; }
    const unsigned short* W2h = a.Wh + OFF_PCONV2;
    const unsigned short* W2l = a.Wl + OFF_PCONV2;
#pragma unroll
    for (int tt = 0; tt < 2; ++tt) {
      int t1 = 2*w + tt;
      int w0 = ((t1*2 + 0)*64 + lane)*8, w1 = ((t1*2 + 1)*64 + lane)*8;
      mfma3(acc[tt], ah0, al0, *(const short8*)(W2h + w0), *(const short8*)(W2l + w0));
      mfma3(acc[tt], ah1, al1, *(const short8*)(W2h + w1), *(const short8*)(W2l + w1));
    }
#pragma unroll
    for (int tt = 0; tt < 2; ++tt) {
      int t1 = 2*w + tt, n = t1*16 + mr;
      float b = a.pconv2_b[n];
      int ks2 = t1 >> 1, q2 = (t1 & 1)*2 + (mr >> 3), jd = mr & 7;
#pragma unroll
      for (int r = 0; r < 4; ++r) {
        int row = q*4 + r;
        float v = acc[tt][r] + b;
        a.pf[(size_t)(m0+row)*128 + n] = v;
        unsigned short hh, ll; split2(v, hh, ll);
        int p = ((ks2*16 + row)*4 + q2)*8 + jd;
        sh_h[p] = hh; sh_l[p] = ll;
      }
    }
    __syncthreads();
    f32x4 acc3[2];
#pragma unroll
    for (int t = 0; t < 2; ++t) { f32x4 z = {0.f,0.f,0.f,0.f}; acc3[t] = z; }
    const unsigned short* W3h = a.Wh + OFF_PSCONV1;
    const unsigned short* W3l = a.Wl + OFF_PSCONV1;
    const unsigned short* W4h = a.Wh + OFF_PSCONV2;
    const unsigned short* W4l = a.Wl + OFF_PSCONV2;
#pragma unroll
    for (int h = 0; h < 2; ++h) {
      f32x4 acc2[2];
#pragma unroll
      for (int t = 0; t < 2; ++t) { f32x4 z = {0.f,0.f,0.f,0.f}; acc2[t] = z; }
#pragma unroll
      for (int ks = 0; ks < 4; ++ks) {
        int ap = ((ks*16 + mr)*4 + q)*8;
        short8 ah = *(const short8*)&sh_h[ap];
        short8 al = *(const short8*)&sh_l[ap];
#pragma unroll
        for (int tt = 0; tt < 2; ++tt) {
          int ts = h*8 + 2*w + tt;
          int wb = ((ts*4 + ks)*64 + lane)*8;
          mfma3(acc2[tt], ah, al, *(const short8*)(W3h + wb), *(const short8*)(W3l + wb));
        }
      }
#pragma unroll
      for (int tt = 0; tt < 2; ++tt) {
        int tl = 2*w + tt;
        int n = h*128 + tl*16 + mr;
        float b = a.psconv1_b[n];
        int ks3 = tl >> 1, q3 = (tl & 1)*2 + (mr >> 3), jd = mr & 7;
#pragma unroll
        for (int r = 0; r < 4; ++r) {
          int row = q*4 + r;
          float v = lrelu(acc2[tt][r] + b);
          unsigned short hh, ll; split2(v, hh, ll);
          int p = 2048 + ((ks3*16 + row)*4 + q3)*8 + jd;
          sh_h[p] = hh; sh_l[p] = ll;
        }
      }
      __syncthreads();
#pragma unroll
      for (int ks = 0; ks < 4; ++ks) {
        int ap = 2048 + ((ks*16 + mr)*4 + q)*8;
        short8 ah = *(const short8*)&sh_h[ap];
        short8 al = *(const short8*)&sh_l[ap];
#pragma unroll
        for (int tt = 0; tt < 2; ++tt) {
          int wb = (((2*w+tt)*8 + h*4 + ks)*64 + lane)*8;
          mfma3(acc3[tt], ah, al, *(const short8*)(W4h + wb), *(const short8*)(W4l + wb));
        }
      }
      __syncthreads();
    }
#pragma unroll
    for (int tt = 0; tt < 2; ++tt) {
      int n = (2*w+tt)*16 + mr;
      float b = a.psconv2_b[n];
#pragma unroll
      for (int r = 0; r < 4; ++r)
        a.Yfp[(size_t)(m0 + q*4 + r)*128 + n] = acc3[tt][r] + b;
    }
  } else {
    int m0 = (cb - 512) * 16;
    int ab = ((m0 >> 4)*64 + lane)*8;
    short8 ah = *(const short8*)(a.feat_h + ab);
    short8 al = *(const short8*)(a.feat_l + ab);
    f32x4 acc = {0.f,0.f,0.f,0.f};
    const unsigned short* W1h = a.Wh + OFF_CONV1;
    const unsigned short* W1l = a.Wl + OFF_CONV1;
    {
      int wb = (w*64 + lane)*8;
      mfma3(acc, ah, al, *(const short8*)(W1h + wb), *(const short8*)(W1l + wb));
    }
    {
      int n = w*16 + mr;
      float b = a.conv1_b[n];
      int ks2 = n >> 5, q2 = (n >> 3) & 3, jd = mr & 7;
#pragma unroll
      for (int r = 0; r < 4; ++r) {
        int row = q*4 + r;
        float v = lrelu(acc[r] + b);
        unsigned short hh, ll; split2(v, hh, ll);
        int p = ((ks2*16 + row)*4 + q2)*8 + jd;
        sh_h[p] = hh; sh_l[p] = ll;
      }
    }
    __syncthreads();
    f32x4 acc2[2];
#pragma unroll
    for (int t = 0; t < 2; ++t) { f32x4 z = {0.f,0.f,0.f,0.f}; acc2[t] = z; }
    const unsigned short* W2h = a.Wh + OFF_CONV2;
    const unsigned short* W2l = a.Wl + OFF_CONV2;
#pragma unroll
    for (int ks = 0; ks < 2; ++ks) {
      int ap = ((ks*16 + mr)*4 + q)*8;
      short8 a2 = *(const short8*)&sh_h[ap];
      short8 a2l = *(const short8*)&sh_l[ap];
#pragma unroll
      for (int tt = 0; tt < 2; ++tt) {
        int wb = (((2*w+tt)*2 + ks)*64 + lane)*8;
        mfma3(acc2[tt], a2, a2l, *(const short8*)(W2h + wb), *(const short8*)(W2l + wb));
      }
    }
#pragma unroll
    for (int tt = 0; tt < 2; ++tt) {
      int n = (2*w+tt)*16 + mr;
      float b = a.conv2_b[n];
#pragma unroll
      for (int r = 0; r < 4; ++r)
        a.Yf[(size_t)(m0 + q*4 + r)*128 + n] = acc2[tt][r] + b;
    }
  }
}

// ---------------- PC: tail tile (pool 18 rows + final + conv3 + head) ----------
__device__ void tail_body(const Args& a, char* smem, int mt, int tid) {
  char* sbuf = smem;                          // 37440 B fin planes + overlays
  short* sjn = (short*)(smem + 37440);        // [18][32] 1152 B
  float* swn = (float*)(smem + 38592);        // [18][32] 2304 B
  int lane = tid & 63, w = tid >> 6;
  int mr = lane & 15, q = lane >> 4;
  int m0 = mt * 16;
  for (int t = tid; t < 18*32; t += 256) {
    int lr = t >> 5, k = t & 31, gr = m0 - 1 + lr;
    if (gr >= 0 && gr < NPT) { sjn[lr*32+k] = (short)a.idx[gr*32+k]; swn[lr*32+k] = a.wsm[gr*32+k]; }
    else { sjn[lr*32+k] = 0; swn[lr*32+k] = 0.f; }
  }
  __syncthreads();
  for (int t = tid; t < 1872; t += 256) {
    int lr, col;
    float4 v4;
    if (t < 1152) {
      lr = t >> 6; int arr = (t >> 5) & 1, cg = t & 31;
      const float* Y = arr ? a.Yf : a.Yfp;
      float ax = -INFINITY, ay = -INFINITY, az = -INFINITY, aw = -INFINITY;
#pragma unroll 8
      for (int k = 0; k < 32; ++k) {
        float4 vv = *(const float4*)&Y[(size_t)sjn[lr*32+k]*128 + cg*4];
        float wk = swn[lr*32+k];
        ax = fmaxf(ax, wk*vv.x); ay = fmaxf(ay, wk*vv.y);
        az = fmaxf(az, wk*vv.z); aw = fmaxf(aw, wk*vv.w);
      }
      v4.x = lrelu(ax); v4.y = lrelu(ay); v4.z = lrelu(az); v4.w = lrelu(aw);
      col = (arr ? 160 : 0) + cg*4;
    } else if (t < 1728) {
      int u = t - 1152; lr = u >> 5; int cg = u & 31;
      int gr = m0 - 1 + lr;
      int gc = gr < 0 ? 0 : (gr >= NPT ? NPT-1 : gr);
      float4 p4 = *(const float4*)&a.pf[(size_t)gc*128 + cg*4];
      v4.x = lrelu(p4.x); v4.y = lrelu(p4.y); v4.z = lrelu(p4.z); v4.w = lrelu(p4.w);
      col = 288 + cg*4;
    } else {
      int u = t - 1728; lr = u >> 3; int cg = u & 7;
      int gr = m0 - 1 + lr;
      int gc = gr < 0 ? 0 : (gr >= NPT ? NPT-1 : gr);
      float4 p4 = *(const float4*)&a.feat[(size_t)gc*32 + cg*4];
      v4.x = lrelu(p4.x); v4.y = lrelu(p4.y); v4.z = lrelu(p4.z); v4.w = lrelu(p4.w);
      col = 128 + cg*4;
    }
    int gr = m0 - 1 + lr;
    if (gr < 0 || gr >= NPT) { v4.x = 0.f; v4.y = 0.f; v4.z = 0.f; v4.w = 0.f; }
    int ks = col >> 5, qq = (col >> 3) & 3, j0 = col & 7;
    char* base = sbuf + (ks*18 + lr)*80 + qq*16 + j0*2;
    short4v hv, lv;
    unsigned short hh, ll;
    split2(v4.x, hh, ll); hv[0] = (short)hh; lv[0] = (short)ll;
    split2(v4.y, hh, ll); hv[1] = (short)hh; lv[1] = (short)ll;
    split2(v4.z, hh, ll); hv[2] = (short)hh; lv[2] = (short)ll;
    split2(v4.w, hh, ll); hv[3] = (short)hh; lv[3] = (short)ll;
    *(short4v*)base = hv;
    *(short4v*)(base + 18720) = lv;
  }
  __syncthreads();
  f32x4 accA[2], accB[2];
#pragma unroll
  for (int t = 0; t < 2; ++t) {
    f32x4 z = {0.f,0.f,0.f,0.f}; accA[t] = z; accB[t] = z;
  }
  const unsigned short* WFh = a.Wh + OFF_FINAL;
  const unsigned short* WFl = a.Wl + OFF_FINAL;
#pragma unroll
  for (int ks = 0; ks < 13; ++ks) {
    int arB = 16 + mr; if (arB > 17) arB = 17;
    const char* pA = sbuf + (ks*18 + mr)*80 + q*16;
    const char* pB = sbuf + (ks*18 + arB)*80 + q*16;
    short8 ahA = *(const short8*)pA;
    short8 alA = *(const short8*)(pA + 18720);
    short8 ahB = *(const short8*)pB;
    short8 alB = *(const short8*)(pB + 18720);
#pragma unroll
    for (int tt = 0; tt < 2; ++tt) {
      int wb = (((2*w+tt)*13 + ks)*64 + lane)*8;
      short8 wh = *(const short8*)(WFh + wb);
      short8 wl = *(const short8*)(WFl + wb);
      mfma3(accA[tt], ahA, alA, wh, wl);
      mfma3(accB[tt], ahB, alB, wh, wl);
    }
  }
  __syncthreads();
#pragma unroll
  for (int tile = 0; tile < 2; ++tile) {
#pragma unroll
    for (int tt = 0; tt < 2; ++tt) {
      int t2 = 2*w + tt, n = t2*16 + mr;
      float b = a.final_b[n];
      int ksA = t2 >> 1, qq = (t2 & 1)*2 + (mr >> 3), jd = mr & 7;
#pragma unroll
      for (int r = 0; r < 4; ++r) {
        int lr = tile*16 + q*4 + r;
        if (lr > 17) continue;
        int gr = m0 - 1 + lr;
        float v = (tile ? accB[tt][r] : accA[tt][r]) + b;
        if (gr < 0 || gr >= NPT) v = 0.f;
        unsigned short hh, ll; split2(v, hh, ll);
        char* p = sbuf + (ksA*18 + lr)*80 + qq*16 + jd*2;
        *(unsigned short*)p = hh;
        *(unsigned short*)(p + 5760) = ll;
      }
    }
  }
  __syncthreads();
  {
    int ks2 = tid >> 6, q2 = (tid >> 4) & 3, mr2 = tid & 15;
    int lr = mr2 + 1;
    const char* p = sbuf + (ks2*18 + lr)*80 + q2*16;
    short8 oh = *(const short8*)p;
    short8 ol = *(const short8*)(p + 5760);
    size_t pos = ((size_t)mt*256 + tid)*8;
    *(short8*)(a.fusedh + pos) = oh;
    *(short8*)(a.fusedl + pos) = ol;
  }
  f32x4 acc3[2];
#pragma unroll
  for (int t = 0; t < 2; ++t) { f32x4 z = {0.f,0.f,0.f,0.f}; acc3[t] = z; }
  const unsigned short* W3h = a.Wh + OFF_W3;
  const unsigned short* W3l = a.Wl + OFF_W3;
#pragma unroll
  for (int ks = 0; ks < 12; ++ks) {
    int tap = ks >> 2, ksA = ks & 3;
    int ar = mr + tap;
    const char* p = sbuf + (ksA*18 + ar)*80 + q*16;
    short8 ah = *(const short8*)p;
    short8 al = *(const short8*)(p + 5760);
#pragma unroll
    for (int tt = 0; tt < 2; ++tt) {
      int wb = (((2*w+tt)*12 + ks)*64 + lane)*8;
      mfma3(acc3[tt], ah, al, *(const short8*)(W3h + wb), *(const short8*)(W3l + wb));
    }
  }
#pragma unroll
  for (int tt = 0; tt < 2; ++tt) {
    int t2 = 2*w + tt, n = t2*16 + mr;
    float b = a.biasc[n];
    int ks2 = t2 >> 1, q2 = (t2 & 1)*2 + (mr >> 3), jd = mr & 7;
#pragma unroll
    for (int r = 0; r < 4; ++r) {
      int row = q*4 + r;
      float v = lrelu(acc3[tt][r] + b);
      unsigned short hh, ll; split2(v, hh, ll);
      char* p = sbuf + 11520 + (ks2*16 + row)*80 + q2*16 + jd*2;
      *(unsigned short*)p = hh;
      *(unsigned short*)(p + 5120) = ll;
    }
  }
  __syncthreads();
  f32x4 acc4 = {0.f,0.f,0.f,0.f};
  const unsigned short* WPh = a.Wh + OFF_W2P;
  const unsigned short* WPl = a.Wl + OFF_W2P;
#pragma unroll
  for (int ks = 0; ks < 4; ++ks) {
    const char* p = sbuf + 11520 + (ks*16 + mr)*80 + q*16;
    short8 ah = *(const short8*)p;
    short8 al = *(const short8*)(p + 5120);
    int wb = ((w*4 + ks)*64 + lane)*8;
    mfma3(acc4, ah, al, *(const short8*)(WPh + wb), *(const short8*)(WPl + wb));
  }
  float hw = (w < 2) ? a.seg3_w[w*16 + mr] : a.dis3_w[(w-2)*16 + mr];
  float bb = a.bias2c[w*16 + mr];
  float* shead = (float*)(sbuf + 21760);
#pragma unroll
  for (int r = 0; r < 4; ++r)
    shead[(w*16 + q*4 + r)*17 + mr] = lrelu(acc4[r] + bb) * hw;
  __syncthreads();
  if (tid < 16) {
    float s = 0.f;
#pragma unroll
    for (int i = 0; i < 16; ++i) s += shead[(tid)*17 + i] + shead[(16 + tid)*17 + i];
    a.o_segp[m0 + tid] = s + a.seg3_b[0];
  } else if (tid < 32) {
    int r2 = tid - 16;
    float s = 0.f;
#pragma unroll
    for (int i = 0; i < 16; ++i) s += shead[(32 + r2)*17 + i] + shead[(48 + r2)*17 + i];
    a.o_disp[m0 + r2] = s + a.dis3_b[0];
  }
}

// ---------------- PD: g-reduction + gated keypoint MLP -------------------------
__device__ void gk_body(const Args& a, char* smem, int b, int tid) {
  float* sred = (float*)smem;                 // 8192 B
  int* slast = (int*)(smem + 8192);
  float* sg = (float*)(smem + 8208);          // 128
  float* s1 = sg + 128;                       // 90
  float* s2 = s1 + 90;                        // 64
  float pg[8] = {0.f,0.f,0.f,0.f,0.f,0.f,0.f,0.f};
  int mrr = tid & 15;
  for (int mi = 0; mi < 16; ++mi) {
    int m = b*16 + mi;
    int row = m*16 + mrr;
    float wrow = a.o_dc[row] * a.seg[row];
    size_t pos = ((size_t)m*256 + tid)*8;
    short8 hv = *(const short8*)(a.fusedh + pos);
    short8 lv = *(const short8*)(a.fusedl + pos);
#pragma unroll
    for (int j = 0; j < 8; ++j)
      pg[j] += (bf2f((unsigned short)hv[j]) + bf2f((unsigned short)lv[j])) * wrow;
  }
#pragma unroll
  for (int j = 0; j < 8; ++j) sred[tid*8 + j] = pg[j];
  __syncthreads();
  if (tid < 128) {
    int ks = tid >> 5, q2 = (tid >> 3) & 3, j = tid & 7;
    float s = 0.f;
#pragma unroll
    for (int mr2 = 0; mr2 < 16; ++mr2) s += sred[((ks<<6) + (q2<<4) + mr2)*8 + j];
    atomicAdd(&a.g[tid], s);
  }
  __threadfence();
  __syncthreads();
  if (tid == 0) *slast = (atomicAdd((int*)(a.g + 128), 1) == 31);
  __syncthreads();
  if (!*slast) return;
  if (tid < 128) sg[tid] = atomicAdd(&a.g[tid], 0.f);
  __syncthreads();
  if (tid < 90) {
    float s = a.lin1_b[tid];
    for (int i = 0; i < 128; ++i) s += sg[i]*a.lin1_w[tid*128+i];
    s1[tid] = lrelu(s);
  }
  __syncthreads();
  if (tid < 64) {
    float s = a.lin2_b[tid];
    for (int i = 0; i < 90; ++i) s += s1[i]*a.lin2_w[tid*90+i];
    s2[tid] = lrelu(s);
  }
  __syncthreads();
  if (tid < 24) {
    float s = a.lin3_b[tid];
    for (int i = 0; i < 64; ++i) s += s2[i]*a.lin3_w[tid*64+i];
    a.o_kp[tid] = s;
  }
}

// ---------------- the single cooperative kernel --------------------------------
__global__ __launch_bounds__(256, 4) void k_all(Args a) {
  __shared__ __align__(16) char smem[40896];
  cg::grid_group grid = cg::this_grid();
  int nb = gridDim.x, bid = blockIdx.x, tid = threadIdx.x;
  // PA: prep (grid-stride over blocks 1..nb-1) + dis_center (block 0)
  if (bid == 0) {
    dc_body(a, smem, tid);
  } else {
    for (int j = (bid-1)*256 + tid; j < PREP_TOTAL; j += (nb-1)*256) prep_item(a, j);
  }
  grid.sync();
  // PB: 2048 knn groups + 1024 chain tiles, grid-strided
  for (int vb = bid; vb < 3072; vb += nb) {
    __syncthreads();
    if (vb < 2048) knn_body(a, smem, vb, tid);
    else           chain_body(a, smem, vb - 2048, tid);
  }
  grid.sync();
  // PC: 512 tail tiles
  for (int mt = bid; mt < 512; mt += nb) {
    __syncthreads();
    tail_body(a, smem, mt, tid);
  }
  grid.sync();
  // PD: 32 g-reduction blocks (last one runs the keypoint MLP)
  for (int vb = bid; vb < 32; vb += nb) {
    __syncthreads();
    gk_body(a, smem, vb, tid);
  }
}

extern "C" void kernel_launch(void* const* d_in, const int* in_sizes, int n_in,
                              void* d_out, int out_size, void* d_ws, size_t ws_size,
                              hipStream_t stream) {
  float* out = (float*)d_out;
  float* ws  = (float*)d_ws;

  Args a;
  a.seg      = (const float*)d_in[0];
  a.img      = (const float*)d_in[1];
  a.cloud    = (const float*)d_in[2];
  a.tvec     = (const float*)d_in[3];
  a.choose   = (const int*)d_in[4];
  a.pconv1_w = (const float*)d_in[5];   a.pconv1_b = (const float*)d_in[6];
  a.pconv2_w = (const float*)d_in[7];   a.pconv2_b = (const float*)d_in[8];
  a.conv1_w  = (const float*)d_in[9];   a.conv1_b  = (const float*)d_in[10];
  a.conv2_w  = (const float*)d_in[11];  a.conv2_b  = (const float*)d_in[12];
  a.psconv1_w= (const float*)d_in[13];  a.psconv1_b= (const float*)d_in[14];
  a.psconv2_w= (const float*)d_in[15];  a.psconv2_b= (const float*)d_in[16];
  a.final_w  = (const float*)d_in[17];  a.final_b  = (const float*)d_in[18];
  a.seg1_w   = (const float*)d_in[19];  a.seg1_b   = (const float*)d_in[20];
  a.seg2_w   = (const float*)d_in[21];  a.seg2_b   = (const float*)d_in[22];
  a.seg3_w   = (const float*)d_in[23];  a.seg3_b   = (const float*)d_in[24];
  a.dis1_w   = (const float*)d_in[25];  a.dis1_b   = (const float*)d_in[26];
  a.dis2_w   = (const float*)d_in[27];  a.dis2_b   = (const float*)d_in[28];
  a.dis3_w   = (const float*)d_in[29];  a.dis3_b   = (const float*)d_in[30];
  a.lin1_w   = (const float*)d_in[31];  a.lin1_b   = (const float*)d_in[32];
  a.lin2_w   = (const float*)d_in[33];  a.lin2_b   = (const float*)d_in[34];
  a.lin3_w   = (const float*)d_in[35];  a.lin3_b   = (const float*)d_in[36];

  // workspace layout (float offsets)
  a.c4     = ws + 0;          // 32768
  a.feat   = ws + 32768;      // 262144
  a.feat_h = (unsigned short*)(ws + 294912);   // 131072 f
  a.feat_l = (unsigned short*)(ws + 425984);   // 131072 f
  a.pf     = ws + 557056;     // 1048576
  a.Yf     = ws + 1605632;    // 1048576
  a.Yfp    = ws + 2654208;    // 1048576
  a.idx    = (int*)(ws + 3702784);   // 262144
  a.wsm    = ws + 3964928;    // 262144
  a.fusedh = (unsigned short*)(ws + 8683520);  // 524288 f
  a.fusedl = (unsigned short*)(ws + 9207808);  // 524288 f
  a.Wh     = (unsigned short*)(ws + 9732096);  // 97280 f
  a.Wl     = (unsigned short*)(ws + 9829376);  // 97280 f
  a.biasc  = ws + 9926656;    // 128
  a.bias2c = ws + 9926784;    // 64
  a.g      = ws + 9926848;    // 129 (g[128] = block counter)

  a.o_kp   = out;             // 24
  a.o_disp = out + 24;        // 8192
  a.o_dc   = out + 8216;      // 8192
  a.o_segp = out + 16408;     // 8192

  int occ = 0;
  hipOccupancyMaxActiveBlocksPerMultiprocessor(&occ, (const void*)k_all, 256, 0);
  int grid = occ * 256;       // 256 CUs on MI355X
  if (grid > 1024) grid = 1024;
  if (grid < 256) grid = 256;

  void* params[] = { (void*)&a };
  hipLaunchCooperativeKernel((const void*)k_all, dim3(grid), dim3(256), params, 0, stream);

  (void)in_sizes; (void)n_in; (void)out_size; (void)ws_size;
}

// Round 12
// 236.164 us; speedup vs baseline: 2.5379x; 2.5379x over previous
//
#include <hip/hip_runtime.h>
#include <math.h>

#define NPT 8192
#define HWIMG 19200
#define KCAP 128

using short8 = __attribute__((ext_vector_type(8))) short;
using short4v = __attribute__((ext_vector_type(4))) short;
using f32x4  = __attribute__((ext_vector_type(4))) float;

__device__ __forceinline__ float lrelu(float x) { return x > 0.f ? x : 0.01f * x; }
__device__ __forceinline__ unsigned short f2bf(float v) {
  unsigned u = __float_as_uint(v);
  return (unsigned short)((u + 0x7fffu + ((u >> 16) & 1u)) >> 16);
}
__device__ __forceinline__ float bf2f(unsigned short h) {
  return __uint_as_float(((unsigned)h) << 16);
}
__device__ __forceinline__ void split2(float v, unsigned short& h, unsigned short& l) {
  h = f2bf(v);
  l = f2bf(v - bf2f(h));
}
__device__ __forceinline__ void mfma3(f32x4& acc, short8 ah, short8 al, short8 wh, short8 wl) {
  acc = __builtin_amdgcn_mfma_f32_16x16x32_bf16(ah, wh, acc, 0, 0, 0);
  acc = __builtin_amdgcn_mfma_f32_16x16x32_bf16(al, wh, acc, 0, 0, 0);
  acc = __builtin_amdgcn_mfma_f32_16x16x32_bf16(ah, wl, acc, 0, 0, 0);
}
__device__ __forceinline__ int swz(int o, int k, int Kc) {
  return ((((o >> 4) * Kc + (k >> 5)) << 6) + (((k >> 3) & 3) << 4) + (o & 15)) * 8 + (k & 7);
}

// weight-plane segment offsets (in shorts)
#define OFF_PCONV2  0
#define OFF_CONV1   8192
#define OFF_CONV2   10240
#define OFF_PSCONV1 18432
#define OFF_PSCONV2 51200
#define OFF_FINAL   83968
#define OFF_W3      137216
#define OFF_W2P     186368

// ---------------- prep: c4, g zero, biases, weight transposes/splits -----------
#define S_C4    NPT
#define S_G     129
#define S_BIASC 128
#define S_B2C   64
#define S_W3    49152
#define S_W2P   8192
#define S_WSPL  OFF_W3
#define PREP_TOTAL (S_C4 + S_G + S_BIASC + S_B2C + S_W3 + S_W2P + S_WSPL)
__global__ void k_prep(const float* __restrict__ cloud,
                       const float* __restrict__ seg1_w, const float* __restrict__ dis1_w,
                       const float* __restrict__ seg1_b, const float* __restrict__ dis1_b,
                       const float* __restrict__ seg2_w, const float* __restrict__ dis2_w,
                       const float* __restrict__ seg2_b, const float* __restrict__ dis2_b,
                       const float* __restrict__ pconv2_w, const float* __restrict__ conv1_w,
                       const float* __restrict__ conv2_w, const float* __restrict__ psconv1_w,
                       const float* __restrict__ psconv2_w, const float* __restrict__ final_w,
                       float* __restrict__ c4, float* __restrict__ g,
                       float* __restrict__ biasc, float* __restrict__ bias2c,
                       unsigned short* __restrict__ Wh, unsigned short* __restrict__ Wl) {
  int j = blockIdx.x * blockDim.x + threadIdx.x;
  if (j < S_C4) {
    float x = cloud[j*3+0], y = cloud[j*3+1], z = cloud[j*3+2];
    float4 v; v.x = x; v.y = y; v.z = z; v.w = x*x + y*y + z*z;
    ((float4*)c4)[j] = v;
    return;
  }
  j -= S_C4;
  if (j < S_G) { g[j] = 0.f; return; }
  j -= S_G;
  if (j < S_BIASC) { biasc[j] = (j < 64) ? seg1_b[j] : dis1_b[j-64]; return; }
  j -= S_BIASC;
  if (j < S_B2C) { bias2c[j] = (j < 32) ? seg2_b[j] : dis2_b[j-32]; return; }
  j -= S_B2C;
  if (j < S_W3) {                          // conv3 weight transpose + split
    int h = j / 24576, r = j - h*24576, o = r / 384, k = r - o*384;
    int t = k >> 7, c = k & 127;
    float v = (h ? dis1_w : seg1_w)[o*384 + c*3 + t];
    unsigned short hh, ll; split2(v, hh, ll);
    int d = OFF_W3 + swz(h*64 + o, k, 12);
    Wh[d] = hh; Wl[d] = ll;
    return;
  }
  j -= S_W3;
  if (j < S_W2P) {                         // W2p block-diagonal + split
    int o = j >> 7, c = j & 127;
    float v = 0.f;
    if (o < 32) { if (c < 64) v = seg2_w[o*64 + c]; }
    else        { if (c >= 64) v = dis2_w[(o-32)*64 + (c-64)]; }
    unsigned short hh, ll; split2(v, hh, ll);
    int d = OFF_W2P + swz(o, c, 4);
    Wh[d] = hh; Wl[d] = ll;
    return;
  }
  j -= S_W2P;
  if (j < S_WSPL) {                        // weight split (swizzled)
    float v; int d;
    if (j < OFF_CONV1) {
      int o = j >> 6, k = j & 63;
      v = pconv2_w[j]; d = OFF_PCONV2 + swz(o, k, 2);
    } else if (j < OFF_CONV2) {
      int jj = j - OFF_CONV1, o = jj >> 5, k = jj & 31;
      v = conv1_w[jj]; d = OFF_CONV1 + swz(o, k, 1);
    } else if (j < OFF_PSCONV1) {
      int jj = j - OFF_CONV2, o = jj >> 6, k = jj & 63;
      v = conv2_w[jj]; d = OFF_CONV2 + swz(o, k, 2);
    } else if (j < OFF_PSCONV2) {
      int jj = j - OFF_PSCONV1, o = jj >> 7, k = jj & 127;
      v = psconv1_w[jj]; d = OFF_PSCONV1 + swz(o, k, 4);
    } else if (j < OFF_FINAL) {
      int jj = j - OFF_PSCONV2, o = jj >> 8, k = jj & 255;
      v = psconv2_w[jj]; d = OFF_PSCONV2 + swz(o, k, 8);
    } else {
      int jj = j - OFF_FINAL, o = jj / 416, k = jj - o*416;
      v = final_w[jj]; d = OFF_FINAL + swz(o, k, 13);
    }
    unsigned short hh, ll; split2(v, hh, ll);
    Wh[d] = hh; Wl[d] = ll;
  }
}

// ---------------- bitonic helpers ---------------------------------------------
__device__ __forceinline__ unsigned bsort32u(unsigned key, int lane) {
#pragma unroll
  for (int k = 2; k <= 64; k <<= 1) {
#pragma unroll
    for (int j = k >> 1; j > 0; j >>= 1) {
      unsigned o = __shfl_xor(key, j, 64);
      bool keepmin = (((lane & j) == 0) == ((lane & k) == 0));
      key = ((o < key) == keepmin) ? o : key;
    }
  }
  return key;
}
__device__ __forceinline__ unsigned long long bsort64(unsigned long long key, int lane) {
#pragma unroll
  for (int k = 2; k <= 64; k <<= 1) {
#pragma unroll
    for (int j = k >> 1; j > 0; j >>= 1) {
      unsigned long long o = __shfl_xor(key, j, 64);
      bool keepmin = (((lane & j) == 0) == ((lane & k) == 0));
      bool omin = o < key;
      key = (omin == keepmin) ? o : key;
    }
  }
  return key;
}
__device__ __forceinline__ unsigned long long bmerge64(unsigned long long key, int lane) {
#pragma unroll
  for (int j = 32; j > 0; j >>= 1) {
    unsigned long long o = __shfl_xor(key, j, 64);
    bool keepmin = ((lane & j) == 0);
    bool omin = o < key;
    key = (omin == keepmin) ? o : key;
  }
  return key;
}

// ---------------- mega: knn (0..2047) | dc (2048) | MLP chains (2049..3072) ----
#define MEGA_GRID 3073
__global__ __launch_bounds__(256) void k_mega(const float4* __restrict__ c4,
                                              int* __restrict__ idxo, float* __restrict__ wo,
                                              const float* __restrict__ cloud,
                                              const float* __restrict__ tvec,
                                              float* __restrict__ dc,
                                              const float* __restrict__ pconv1_w, const float* __restrict__ pconv1_b,
                                              const float* __restrict__ pconv2_b, const float* __restrict__ psconv1_b,
                                              const float* __restrict__ psconv2_b,
                                              const float* __restrict__ img, const int* __restrict__ choose,
                                              const float* __restrict__ conv1_b, const float* __restrict__ conv2_b,
                                              const unsigned short* __restrict__ Wh,
                                              const unsigned short* __restrict__ Wl,
                                              float* __restrict__ pf, float* __restrict__ Yfp,
                                              float* __restrict__ Yf) {
  __shared__ __align__(16) char smem[16384];
  int tid = threadIdx.x, lane = tid & 63, w = tid >> 6;
  int mr = lane & 15, q = lane >> 4;
  if (blockIdx.x > 2048) {
    unsigned short* sh_h = (unsigned short*)smem;
    unsigned short* sh_l = (unsigned short*)(smem + 8192);
    int cb = blockIdx.x - 2049;
    if (cb < 512) {
      int m0 = cb * 16;
      // stage 1: pconv1 (K=3) directly in A-frag ownership
      float4 cp = c4[m0 + mr];
      short8 ah0, al0, ah1, al1;
#pragma unroll
      for (int j = 0; j < 8; ++j) {
        int c0 = q*8 + j, c1 = 32 + q*8 + j;
        float v0 = lrelu(fmaf(cp.x, pconv1_w[c0*3+0], fmaf(cp.y, pconv1_w[c0*3+1],
                          fmaf(cp.z, pconv1_w[c0*3+2], pconv1_b[c0]))));
        float v1 = lrelu(fmaf(cp.x, pconv1_w[c1*3+0], fmaf(cp.y, pconv1_w[c1*3+1],
                          fmaf(cp.z, pconv1_w[c1*3+2], pconv1_b[c1]))));
        unsigned short hh, ll;
        split2(v0, hh, ll); ah0[j] = (short)hh; al0[j] = (short)ll;
        split2(v1, hh, ll); ah1[j] = (short)hh; al1[j] = (short)ll;
      }
      // stage 2: pconv2 (K=64, N=128)
      f32x4 acc[2];
#pragma unroll
      for (int t = 0; t < 2; ++t) { f32x4 z = {0.f,0.f,0.f,0.f}; acc[t] = z; }
      const unsigned short* W2h = Wh + OFF_PCONV2;
      const unsigned short* W2l = Wl + OFF_PCONV2;
#pragma unroll
      for (int tt = 0; tt < 2; ++tt) {
        int t1 = 2*w + tt;
        int w0 = ((t1*2 + 0)*64 + lane)*8, w1 = ((t1*2 + 1)*64 + lane)*8;
        mfma3(acc[tt], ah0, al0, *(const short8*)(W2h + w0), *(const short8*)(W2l + w0));
        mfma3(acc[tt], ah1, al1, *(const short8*)(W2h + w1), *(const short8*)(W2l + w1));
      }
#pragma unroll
      for (int tt = 0; tt < 2; ++tt) {
        int t1 = 2*w + tt, n = t1*16 + mr;
        float b = pconv2_b[n];
        int ks2 = t1 >> 1, q2 = (t1 & 1)*2 + (mr >> 3), jd = mr & 7;
#pragma unroll
        for (int r = 0; r < 4; ++r) {
          int row = q*4 + r;
          float v = acc[tt][r] + b;
          pf[(size_t)(m0+row)*128 + n] = v;
          unsigned short hh, ll; split2(v, hh, ll);
          int p = ((ks2*16 + row)*4 + q2)*8 + jd;
          sh_h[p] = hh; sh_l[p] = ll;
        }
      }
      __syncthreads();
      // stages 3+4: psconv1/psconv2 in two 128-col halves (acc3 persists)
      f32x4 acc3[2];
#pragma unroll
      for (int t = 0; t < 2; ++t) { f32x4 z = {0.f,0.f,0.f,0.f}; acc3[t] = z; }
      const unsigned short* W3h = Wh + OFF_PSCONV1;
      const unsigned short* W3l = Wl + OFF_PSCONV1;
      const unsigned short* W4h = Wh + OFF_PSCONV2;
      const unsigned short* W4l = Wl + OFF_PSCONV2;
#pragma unroll
      for (int h = 0; h < 2; ++h) {
        f32x4 acc2[2];
#pragma unroll
        for (int t = 0; t < 2; ++t) { f32x4 z = {0.f,0.f,0.f,0.f}; acc2[t] = z; }
#pragma unroll
        for (int ks = 0; ks < 4; ++ks) {
          int ap = ((ks*16 + mr)*4 + q)*8;
          short8 ah = *(const short8*)&sh_h[ap];
          short8 al = *(const short8*)&sh_l[ap];
#pragma unroll
          for (int tt = 0; tt < 2; ++tt) {
            int ts = h*8 + 2*w + tt;
            int wb = ((ts*4 + ks)*64 + lane)*8;
            mfma3(acc2[tt], ah, al, *(const short8*)(W3h + wb), *(const short8*)(W3l + wb));
          }
        }
#pragma unroll
        for (int tt = 0; tt < 2; ++tt) {
          int tl = 2*w + tt;
          int n = h*128 + tl*16 + mr;
          float b = psconv1_b[n];
          int ks3 = tl >> 1, q3 = (tl & 1)*2 + (mr >> 3), jd = mr & 7;
#pragma unroll
          for (int r = 0; r < 4; ++r) {
            int row = q*4 + r;
            float v = lrelu(acc2[tt][r] + b);
            unsigned short hh, ll; split2(v, hh, ll);
            int p = 2048 + ((ks3*16 + row)*4 + q3)*8 + jd;
            sh_h[p] = hh; sh_l[p] = ll;
          }
        }
        __syncthreads();
#pragma unroll
        for (int ks = 0; ks < 4; ++ks) {
          int ap = 2048 + ((ks*16 + mr)*4 + q)*8;
          short8 ah = *(const short8*)&sh_h[ap];
          short8 al = *(const short8*)&sh_l[ap];
#pragma unroll
          for (int tt = 0; tt < 2; ++tt) {
            int wb = (((2*w+tt)*8 + h*4 + ks)*64 + lane)*8;
            mfma3(acc3[tt], ah, al, *(const short8*)(W4h + wb), *(const short8*)(W4l + wb));
          }
        }
        __syncthreads();
      }
#pragma unroll
      for (int tt = 0; tt < 2; ++tt) {
        int n = (2*w+tt)*16 + mr;
        float b = psconv2_b[n];
#pragma unroll
        for (int r = 0; r < 4; ++r)
          Yfp[(size_t)(m0 + q*4 + r)*128 + n] = acc3[tt][r] + b;
      }
    } else {
      int m0 = (cb - 512) * 16;
      // conv1 (K=32): stage feat rows m0..m0+15 directly from img into LDS frags
      for (int t = tid; t < 512; t += 256) {
        int rw = t >> 5, ch = t & 31;
        float v = img[ch*HWIMG + choose[m0 + rw]];
        unsigned short hh, ll; split2(v, hh, ll);
        int p = 1024 + ((ch >> 3)*16 + rw)*8 + (ch & 7);
        sh_h[p] = hh; sh_l[p] = ll;
      }
      __syncthreads();
      short8 ah = *(const short8*)&sh_h[1024 + (q*16 + mr)*8];
      short8 al = *(const short8*)&sh_l[1024 + (q*16 + mr)*8];
      f32x4 acc = {0.f,0.f,0.f,0.f};
      const unsigned short* W1h = Wh + OFF_CONV1;
      const unsigned short* W1l = Wl + OFF_CONV1;
      {
        int wb = (w*64 + lane)*8;
        mfma3(acc, ah, al, *(const short8*)(W1h + wb), *(const short8*)(W1l + wb));
      }
      __syncthreads();
      {
        int n = w*16 + mr;
        float b = conv1_b[n];
        int ks2 = n >> 5, q2 = (n >> 3) & 3, jd = mr & 7;
#pragma unroll
        for (int r = 0; r < 4; ++r) {
          int row = q*4 + r;
          float v = lrelu(acc[r] + b);
          unsigned short hh, ll; split2(v, hh, ll);
          int p = ((ks2*16 + row)*4 + q2)*8 + jd;
          sh_h[p] = hh; sh_l[p] = ll;
        }
      }
      __syncthreads();
      f32x4 acc2[2];
#pragma unroll
      for (int t = 0; t < 2; ++t) { f32x4 z = {0.f,0.f,0.f,0.f}; acc2[t] = z; }
      const unsigned short* W2h = Wh + OFF_CONV2;
      const unsigned short* W2l = Wl + OFF_CONV2;
#pragma unroll
      for (int ks = 0; ks < 2; ++ks) {
        int ap = ((ks*16 + mr)*4 + q)*8;
        short8 a2 = *(const short8*)&sh_h[ap];
        short8 a2l = *(const short8*)&sh_l[ap];
#pragma unroll
        for (int tt = 0; tt < 2; ++tt) {
          int wb = (((2*w+tt)*2 + ks)*64 + lane)*8;
          mfma3(acc2[tt], a2, a2l, *(const short8*)(W2h + wb), *(const short8*)(W2l + wb));
        }
      }
#pragma unroll
      for (int tt = 0; tt < 2; ++tt) {
        int n = (2*w+tt)*16 + mr;
        float b = conv2_b[n];
#pragma unroll
        for (int r = 0; r < 4; ++r)
          Yf[(size_t)(m0 + q*4 + r)*128 + n] = acc2[tt][r] + b;
      }
    }
    return;
  }
  if (blockIdx.x == 2048) {
    float* sred = (float*)smem;
    float tx = tvec[0], ty = tvec[1], tz = tvec[2];
    float v[32];
    float m = -INFINITY;
#pragma unroll
    for (int i2 = 0; i2 < 32; ++i2) {
      int n = i2*256 + tid;
      float ax = cloud[n*3+0] + tx, ay = cloud[n*3+1] + ty, az = cloud[n*3+2] + tz;
      v[i2] = sqrtf(ax*ax + ay*ay + az*az);
      m = fmaxf(m, v[i2]);
    }
#pragma unroll
    for (int o = 1; o < 64; o <<= 1) m = fmaxf(m, __shfl_xor(m, o, 64));
    if (lane == 0) sred[w] = m;
    __syncthreads();
    m = fmaxf(fmaxf(sred[0], sred[1]), fmaxf(sred[2], sred[3]));
    __syncthreads();
    float s = 0.f;
#pragma unroll
    for (int i2 = 0; i2 < 32; ++i2) { v[i2] = expf(v[i2] - m); s += v[i2]; }
#pragma unroll
    for (int o = 1; o < 64; o <<= 1) s += __shfl_xor(s, o, 64);
    if (lane == 0) sred[w] = s;
    __syncthreads();
    s = sred[0] + sred[1] + sred[2] + sred[3];
#pragma unroll
    for (int i2 = 0; i2 < 32; ++i2) dc[i2*256 + tid] = v[i2] / s;
    return;
  }
  // knn
  float (*smin)[256] = (float(*)[256])smem;
  float* sTv = (float*)(smem + 4096);
  int*   scnt = (int*)(smem + 4112);
  float (*sd)[KCAP] = (float(*)[KCAP])(smem + 4128);
  int   (*sj)[KCAP] = (int(*)[KCAP])(smem + 6176);
  int q0 = blockIdx.x * 4;
  float4 p0 = c4[q0], p1 = c4[q0+1], p2 = c4[q0+2], p3 = c4[q0+3];
  float p0x = -2.f*p0.x, p0y = -2.f*p0.y, p0z = -2.f*p0.z;
  float p1x = -2.f*p1.x, p1y = -2.f*p1.y, p1z = -2.f*p1.z;
  float p2x = -2.f*p2.x, p2y = -2.f*p2.y, p2z = -2.f*p2.z;
  float p3x = -2.f*p3.x, p3y = -2.f*p3.y, p3z = -2.f*p3.z;
#define DDOT(PX,PY,PZ,PW,CJ) fmaf(PX,(CJ).x, fmaf(PY,(CJ).y, fmaf(PZ,(CJ).z, PW + (CJ).w)))
  float m0 = INFINITY, m1 = INFINITY, m2 = INFINITY, m3 = INFINITY;
  for (int t = 0; t < 32; ++t) {
    float4 cj = c4[t*256 + tid];
    m0 = fminf(m0, DDOT(p0x,p0y,p0z,p0.w,cj));
    m1 = fminf(m1, DDOT(p1x,p1y,p1z,p1.w,cj));
    m2 = fminf(m2, DDOT(p2x,p2y,p2z,p2.w,cj));
    m3 = fminf(m3, DDOT(p3x,p3y,p3z,p3.w,cj));
  }
  smin[0][tid] = m0; smin[1][tid] = m1; smin[2][tid] = m2; smin[3][tid] = m3;
  if (tid < 4) scnt[tid] = 0;
  __syncthreads();
  {
    float4 vv = *(const float4*)&smin[w][lane*4];
    float m4 = fmaxf(fminf(fminf(vv.x, vv.y), fminf(vv.z, vv.w)), 0.f);
    unsigned key = bsort32u(__float_as_uint(m4), lane);
    float T = __uint_as_float(__shfl(key, 31, 64));
    if (lane == 0) sTv[w] = T * (1.f + 2e-5f) + 4e-5f;
  }
  __syncthreads();
  float T0 = sTv[0], T1 = sTv[1], T2 = sTv[2], T3 = sTv[3];
  for (int t = 0; t < 32; ++t) {
    int j = t*256 + tid;
    float4 cj = c4[j];
    float d;
#define APPEND(Q, P) { \
    float dx_ = (P).x-cj.x, dy_ = (P).y-cj.y, dz_ = (P).z-cj.z; \
    float de_ = dx_*dx_ + dy_*dy_ + dz_*dz_; \
    int p_ = atomicAdd(&scnt[Q],1); if (p_ < KCAP) { sd[Q][p_] = de_; sj[Q][p_] = j; } }
    d = DDOT(p0x,p0y,p0z,p0.w,cj); if (d <= T0) APPEND(0, p0);
    d = DDOT(p1x,p1y,p1z,p1.w,cj); if (d <= T1) APPEND(1, p1);
    d = DDOT(p2x,p2y,p2z,p2.w,cj); if (d <= T2) APPEND(2, p2);
    d = DDOT(p3x,p3y,p3z,p3.w,cj); if (d <= T3) APPEND(3, p3);
  }
  __syncthreads();
  int M = scnt[w]; if (M > KCAP) M = KCAP;
  unsigned long long key = (lane < M)
      ? (((unsigned long long)__float_as_uint(sd[w][lane]) << 32) | (unsigned)sj[w][lane])
      : ~0ull;
  key = bsort64(key, lane);
  for (int base = 64; base < M; base += 64) {
    unsigned long long nk = (base + lane < M)
        ? (((unsigned long long)__float_as_uint(sd[w][base+lane]) << 32) | (unsigned)sj[w][base+lane])
        : ~0ull;
    nk = bsort64(nk, lane);
    nk = __shfl_xor(nk, 63, 64);
    key = key < nk ? key : nk;
    key = bmerge64(key, lane);
  }
  float dsel = __uint_as_float((unsigned)(key >> 32));
  int   jsel = (int)(unsigned)(key & 0xffffffffu);
  float v = -sqrtf(dsel);
  float mx = v;
#pragma unroll
  for (int o = 1; o < 32; o <<= 1) mx = fmaxf(mx, __shfl_xor(mx, o, 64));
  float e = expf(v - mx);
  float s = e;
#pragma unroll
  for (int o = 1; o < 32; o <<= 1) s += __shfl_xor(s, o, 64);
  if (lane < 32) {
    int qd = q0 + w;
    wo[qd*32 + lane] = e / s;
    idxo[qd*32 + lane] = jsel;
  }
}

// ---------------- tail: pool(18) + final + conv3 + head + local g-partial ------
// LDS fin planes [0,37440); overlay after final GEMM: fused (stride 5760),
// t1 @11520 (stride 5120), shead @21760, gpart @26112.
__global__ __launch_bounds__(256) void k_tail(const float* __restrict__ Yf,
                                              const float* __restrict__ Yfp,
                                              const float* __restrict__ img,
                                              const int* __restrict__ choose,
                                              const float* __restrict__ pf,
                                              const int* __restrict__ idx,
                                              const float* __restrict__ wsm,
                                              const unsigned short* __restrict__ Wh,
                                              const unsigned short* __restrict__ Wl,
                                              const float* __restrict__ final_b,
                                              const float* __restrict__ biasc,
                                              const float* __restrict__ bias2c,
                                              const float* __restrict__ segw, const float* __restrict__ segb,
                                              const float* __restrict__ disw, const float* __restrict__ disb,
                                              const float* __restrict__ dc, const float* __restrict__ seg,
                                              float* __restrict__ g,
                                              float* __restrict__ osegp, float* __restrict__ odisp) {
  __shared__ int sjn[18][32];
  __shared__ float swn[18][32];
  __shared__ __align__(16) char sbuf[37440];
  int tid = threadIdx.x, lane = tid & 63, w = tid >> 6;
  int mr = lane & 15, q = lane >> 4;
  int mt = blockIdx.x, m0 = mt * 16;
  // P1: neighbor lists for 18 rows (halo +-1)
  for (int t = tid; t < 18*32; t += 256) {
    int lr = t >> 5, k = t & 31, gr = m0 - 1 + lr;
    if (gr >= 0 && gr < NPT) { sjn[lr][k] = idx[gr*32+k]; swn[lr][k] = wsm[gr*32+k]; }
    else { sjn[lr][k] = 0; swn[lr][k] = 0.f; }
  }
  __syncthreads();
  // P2: build fin[18][416] split planes in LDS
  for (int t = tid; t < 1872; t += 256) {
    int lr, col;
    float4 v4;
    if (t < 1152) {
      lr = t >> 6; int arr = (t >> 5) & 1, cg = t & 31;
      const float* Y = arr ? Yf : Yfp;
      float ax = -INFINITY, ay = -INFINITY, az = -INFINITY, aw = -INFINITY;
#pragma unroll 8
      for (int k = 0; k < 32; ++k) {
        float4 vv = *(const float4*)&Y[(size_t)sjn[lr][k]*128 + cg*4];
        float wk = swn[lr][k];
        ax = fmaxf(ax, wk*vv.x); ay = fmaxf(ay, wk*vv.y);
        az = fmaxf(az, wk*vv.z); aw = fmaxf(aw, wk*vv.w);
      }
      v4.x = lrelu(ax); v4.y = lrelu(ay); v4.z = lrelu(az); v4.w = lrelu(aw);
      col = (arr ? 160 : 0) + cg*4;
    } else if (t < 1728) {
      int u = t - 1152; lr = u >> 5; int cg = u & 31;
      int gr = m0 - 1 + lr;
      int gc = gr < 0 ? 0 : (gr >= NPT ? NPT-1 : gr);
      float4 p4 = *(const float4*)&pf[(size_t)gc*128 + cg*4];
      v4.x = lrelu(p4.x); v4.y = lrelu(p4.y); v4.z = lrelu(p4.z); v4.w = lrelu(p4.w);
      col = 288 + cg*4;
    } else {
      int u = t - 1728; lr = u >> 3; int cg = u & 7;
      int gr = m0 - 1 + lr;
      int gc = gr < 0 ? 0 : (gr >= NPT ? NPT-1 : gr);
      int ix = choose[gc];
      v4.x = lrelu(img[(cg*4+0)*HWIMG + ix]);
      v4.y = lrelu(img[(cg*4+1)*HWIMG + ix]);
      v4.z = lrelu(img[(cg*4+2)*HWIMG + ix]);
      v4.w = lrelu(img[(cg*4+3)*HWIMG + ix]);
      col = 128 + cg*4;
    }
    int gr = m0 - 1 + lr;
    if (gr < 0 || gr >= NPT) { v4.x = 0.f; v4.y = 0.f; v4.z = 0.f; v4.w = 0.f; }
    int ks = col >> 5, qq = (col >> 3) & 3, j0 = col & 7;
    char* base = sbuf + (ks*18 + lr)*80 + qq*16 + j0*2;
    short4v hv, lv;
    unsigned short hh, ll;
    split2(v4.x, hh, ll); hv[0] = (short)hh; lv[0] = (short)ll;
    split2(v4.y, hh, ll); hv[1] = (short)hh; lv[1] = (short)ll;
    split2(v4.z, hh, ll); hv[2] = (short)hh; lv[2] = (short)ll;
    split2(v4.w, hh, ll); hv[3] = (short)hh; lv[3] = (short)ll;
    *(short4v*)base = hv;
    *(short4v*)(base + 18720) = lv;
  }
  __syncthreads();
  // dc*seg staging for the g-partial (swn free after P2's sync barrier above)
  float* dcseg = &swn[0][0];
  if (tid < 16) dcseg[tid] = dc[m0 + tid] * seg[m0 + tid];
  // P3: final GEMM (K=416) on 2 m-tiles (rows 0..15 and 16..17 clamped)
  f32x4 accA[2], accB[2];
#pragma unroll
  for (int t = 0; t < 2; ++t) {
    f32x4 z = {0.f,0.f,0.f,0.f}; accA[t] = z; accB[t] = z;
  }
  const unsigned short* WFh = Wh + OFF_FINAL;
  const unsigned short* WFl = Wl + OFF_FINAL;
#pragma unroll
  for (int ks = 0; ks < 13; ++ks) {
    int arB = 16 + mr; if (arB > 17) arB = 17;
    const char* pA = sbuf + (ks*18 + mr)*80 + q*16;
    const char* pB = sbuf + (ks*18 + arB)*80 + q*16;
    short8 ahA = *(const short8*)pA;
    short8 alA = *(const short8*)(pA + 18720);
    short8 ahB = *(const short8*)pB;
    short8 alB = *(const short8*)(pB + 18720);
#pragma unroll
    for (int tt = 0; tt < 2; ++tt) {
      int wb = (((2*w+tt)*13 + ks)*64 + lane)*8;
      short8 wh = *(const short8*)(WFh + wb);
      short8 wl = *(const short8*)(WFl + wb);
      mfma3(accA[tt], ahA, alA, wh, wl);
      mfma3(accB[tt], ahB, alB, wh, wl);
    }
  }
  __syncthreads();
  // P3b: write fused split planes to LDS overlay (OOB rows zeroed = conv pad)
#pragma unroll
  for (int tile = 0; tile < 2; ++tile) {
#pragma unroll
    for (int tt = 0; tt < 2; ++tt) {
      int t2 = 2*w + tt, n = t2*16 + mr;
      float b = final_b[n];
      int ksA = t2 >> 1, qq = (t2 & 1)*2 + (mr >> 3), jd = mr & 7;
#pragma unroll
      for (int r = 0; r < 4; ++r) {
        int lr = tile*16 + q*4 + r;
        if (lr > 17) continue;
        int gr = m0 - 1 + lr;
        float v = (tile ? accB[tt][r] : accA[tt][r]) + b;
        if (gr < 0 || gr >= NPT) v = 0.f;
        unsigned short hh, ll; split2(v, hh, ll);
        char* p = sbuf + (ksA*18 + lr)*80 + qq*16 + jd*2;
        *(unsigned short*)p = hh;
        *(unsigned short*)(p + 5760) = ll;
      }
    }
  }
  __syncthreads();
  // P4: conv3 from local fused (halo resident)
  f32x4 acc3[2];
#pragma unroll
  for (int t = 0; t < 2; ++t) { f32x4 z = {0.f,0.f,0.f,0.f}; acc3[t] = z; }
  const unsigned short* W3h = Wh + OFF_W3;
  const unsigned short* W3l = Wl + OFF_W3;
#pragma unroll
  for (int ks = 0; ks < 12; ++ks) {
    int tap = ks >> 2, ksA = ks & 3;
    int ar = mr + tap;
    const char* p = sbuf + (ksA*18 + ar)*80 + q*16;
    short8 ah = *(const short8*)p;
    short8 al = *(const short8*)(p + 5760);
#pragma unroll
    for (int tt = 0; tt < 2; ++tt) {
      int wb = (((2*w+tt)*12 + ks)*64 + lane)*8;
      mfma3(acc3[tt], ah, al, *(const short8*)(W3h + wb), *(const short8*)(W3l + wb));
    }
  }
#pragma unroll
  for (int tt = 0; tt < 2; ++tt) {
    int t2 = 2*w + tt, n = t2*16 + mr;
    float b = biasc[n];
    int ks2 = t2 >> 1, q2 = (t2 & 1)*2 + (mr >> 3), jd = mr & 7;
#pragma unroll
    for (int r = 0; r < 4; ++r) {
      int row = q*4 + r;
      float v = lrelu(acc3[tt][r] + b);
      unsigned short hh, ll; split2(v, hh, ll);
      char* p = sbuf + 11520 + (ks2*16 + row)*80 + q2*16 + jd*2;
      *(unsigned short*)p = hh;
      *(unsigned short*)(p + 5120) = ll;
    }
  }
  __syncthreads();
  // P5: head GEMM + fused 1-wide heads
  f32x4 acc4 = {0.f,0.f,0.f,0.f};
  const unsigned short* WPh = Wh + OFF_W2P;
  const unsigned short* WPl = Wl + OFF_W2P;
#pragma unroll
  for (int ks = 0; ks < 4; ++ks) {
    const char* p = sbuf + 11520 + (ks*16 + mr)*80 + q*16;
    short8 ah = *(const short8*)p;
    short8 al = *(const short8*)(p + 5120);
    int wb = ((w*4 + ks)*64 + lane)*8;
    mfma3(acc4, ah, al, *(const short8*)(WPh + wb), *(const short8*)(WPl + wb));
  }
  float hw = (w < 2) ? segw[w*16 + mr] : disw[(w-2)*16 + mr];
  float bb = bias2c[w*16 + mr];
  float* shead = (float*)(sbuf + 21760);   // [4][16][17]
#pragma unroll
  for (int r = 0; r < 4; ++r)
    shead[(w*16 + q*4 + r)*17 + mr] = lrelu(acc4[r] + bb) * hw;
  __syncthreads();
  if (tid < 16) {
    float s = 0.f;
#pragma unroll
    for (int i = 0; i < 16; ++i) s += shead[(tid)*17 + i] + shead[(16 + tid)*17 + i];
    osegp[m0 + tid] = s + segb[0];
  } else if (tid < 32) {
    int r2 = tid - 16;
    float s = 0.f;
#pragma unroll
    for (int i = 0; i < 16; ++i) s += shead[(32 + r2)*17 + i] + shead[(48 + r2)*17 + i];
    odisp[m0 + r2] = s + disb[0];
  }
  // P6: block-local g contribution from the LDS fused planes (no global round
  // trip, no fence: visibility to the later k_kp kernel is guaranteed at the
  // kernel boundary; fp32 atomic order is already order-free for this sum)
  {
    float* gpart = (float*)(sbuf + 26112);   // 256 floats
    int c = tid & 127, half = tid >> 7;
    int ksA = c >> 5, qq = (c >> 3) & 3, jd = c & 7;
    float acc = 0.f;
#pragma unroll
    for (int r8 = 0; r8 < 8; ++r8) {
      int row = half*8 + r8;
      const char* p = sbuf + (ksA*18 + (row + 1))*80 + qq*16 + jd*2;
      float v = bf2f(*(const unsigned short*)p) + bf2f(*(const unsigned short*)(p + 5760));
      acc += v * dcseg[row];
    }
    gpart[tid] = acc;
    __syncthreads();
    if (tid < 128) atomicAdd(&g[tid], gpart[tid] + gpart[tid + 128]);
  }
}

// ---------------- kp: keypoint MLP 128->90->64->24 (g complete at launch) ------
__global__ __launch_bounds__(128) void k_kp(const float* __restrict__ g,
                                            const float* __restrict__ l1w, const float* __restrict__ l1b,
                                            const float* __restrict__ l2w, const float* __restrict__ l2b,
                                            const float* __restrict__ l3w, const float* __restrict__ l3b,
                                            float* __restrict__ outp) {
  __shared__ float sg[128], s1[90], s2[64];
  int tid = threadIdx.x;
  sg[tid] = g[tid];
  __syncthreads();
  if (tid < 90) {
    float a = l1b[tid];
    for (int i = 0; i < 128; ++i) a += sg[i]*l1w[tid*128+i];
    s1[tid] = lrelu(a);
  }
  __syncthreads();
  if (tid < 64) {
    float a = l2b[tid];
    for (int i = 0; i < 90; ++i) a += s1[i]*l2w[tid*90+i];
    s2[tid] = lrelu(a);
  }
  __syncthreads();
  if (tid < 24) {
    float a = l3b[tid];
    for (int i = 0; i < 64; ++i) a += s2[i]*l3w[tid*64+i];
    outp[tid] = a;
  }
}

extern "C" void kernel_launch(void* const* d_in, const int* in_sizes, int n_in,
                              void* d_out, int out_size, void* d_ws, size_t ws_size,
                              hipStream_t stream) {
  const float* seg      = (const float*)d_in[0];
  const float* img      = (const float*)d_in[1];
  const float* cloud    = (const float*)d_in[2];
  const float* tvec     = (const float*)d_in[3];
  const int*   choose   = (const int*)d_in[4];
  const float* pconv1_w = (const float*)d_in[5];
  const float* pconv1_b = (const float*)d_in[6];
  const float* pconv2_w = (const float*)d_in[7];
  const float* pconv2_b = (const float*)d_in[8];
  const float* conv1_w  = (const float*)d_in[9];
  const float* conv1_b  = (const float*)d_in[10];
  const float* conv2_w  = (const float*)d_in[11];
  const float* conv2_b  = (const float*)d_in[12];
  const float* psconv1_w= (const float*)d_in[13];
  const float* psconv1_b= (const float*)d_in[14];
  const float* psconv2_w= (const float*)d_in[15];
  const float* psconv2_b= (const float*)d_in[16];
  const float* final_w  = (const float*)d_in[17];
  const float* final_b  = (const float*)d_in[18];
  const float* seg1_w   = (const float*)d_in[19];
  const float* seg1_b   = (const float*)d_in[20];
  const float* seg2_w   = (const float*)d_in[21];
  const float* seg2_b   = (const float*)d_in[22];
  const float* seg3_w   = (const float*)d_in[23];
  const float* seg3_b   = (const float*)d_in[24];
  const float* dis1_w   = (const float*)d_in[25];
  const float* dis1_b   = (const float*)d_in[26];
  const float* dis2_w   = (const float*)d_in[27];
  const float* dis2_b   = (const float*)d_in[28];
  const float* dis3_w   = (const float*)d_in[29];
  const float* dis3_b   = (const float*)d_in[30];
  const float* lin1_w   = (const float*)d_in[31];
  const float* lin1_b   = (const float*)d_in[32];
  const float* lin2_w   = (const float*)d_in[33];
  const float* lin2_b   = (const float*)d_in[34];
  const float* lin3_w   = (const float*)d_in[35];
  const float* lin3_b   = (const float*)d_in[36];

  float* out = (float*)d_out;
  float* ws  = (float*)d_ws;

  // workspace layout (float offsets)
  float* c4     = ws + 0;          // 32768
  float* pf     = ws + 32768;      // 1048576
  float* Yf     = ws + 1081344;    // 1048576
  float* Yfp    = ws + 2129920;    // 1048576
  int*   idx    = (int*)(ws + 3178496);   // 262144
  float* wsm    = ws + 3440640;    // 262144
  unsigned short* Wh = (unsigned short*)(ws + 3702784);   // 97280 f
  unsigned short* Wl = (unsigned short*)(ws + 3800064);   // 97280 f
  float* biasc  = ws + 3897344;    // 128
  float* bias2c = ws + 3897472;    // 64
  float* g      = ws + 3897536;    // 129

  float* o_kp   = out;             // 24
  float* o_disp = out + 24;        // 8192
  float* o_dc   = out + 8216;      // 8192
  float* o_segp = out + 16408;     // 8192

  k_prep<<<(PREP_TOTAL + 255)/256, 256, 0, stream>>>(
      cloud, seg1_w, dis1_w, seg1_b, dis1_b,
      seg2_w, dis2_w, seg2_b, dis2_b,
      pconv2_w, conv1_w, conv2_w, psconv1_w, psconv2_w, final_w,
      c4, g, biasc, bias2c, Wh, Wl);

  k_mega<<<MEGA_GRID, 256, 0, stream>>>(
      (const float4*)c4, idx, wsm, cloud, tvec, o_dc,
      pconv1_w, pconv1_b, pconv2_b, psconv1_b, psconv2_b,
      img, choose, conv1_b, conv2_b, Wh, Wl, pf, Yfp, Yf);

  k_tail<<<512, 256, 0, stream>>>(
      Yf, Yfp, img, choose, pf, idx, wsm, Wh, Wl,
      final_b, biasc, bias2c, seg3_w, seg3_b, dis3_w, dis3_b,
      o_dc, seg, g, o_segp, o_disp);

  k_kp<<<1, 128, 0, stream>>>(g, lin1_w, lin1_b, lin2_w, lin2_b, lin3_w, lin3_b, o_kp);

  (void)in_sizes; (void)n_in; (void)out_size; (void)ws_size;
}